// Round 3
// baseline (449.606 us; speedup 1.0000x reference)
//
#include <hip/hip_runtime.h>
#include <hip/hip_fp16.h>

// B=8, S=2048, DMODEL=1024, DK=128
#define SEQ 2048
#define DMODEL 1024
#define DK 128

typedef _Float16 f16x8 __attribute__((ext_vector_type(8)));
typedef float    f32x4 __attribute__((ext_vector_type(4)));

#define L2E 1.44269504088896340736f

// ---------------- workspace element offsets (fp16 elements) ----------------
// w16: [3][128][1024]           at 0        (393216)
// q:   [16384][128]             at 393216
// k:   [16384][128]             at 2490368
// vt:  [8][128][2048]           at 4587520  (end 6684672 f16 = 13369344 B)
// then fp32 partials: Opart[J][16384][128], ml[J][16384][2]
#define WS_Q  393216
#define WS_K  2490368
#define WS_VT 4587520
#define WS_F16_BYTES 13369344ull

// ---------------------------------------------------------------------------
// Kernel 1: convert Wq/Wk/Wv fp32 -> fp16.  Scale 1/sqrt(dk) folded into Wq.
// ---------------------------------------------------------------------------
__global__ __launch_bounds__(256) void wconv_kernel(
    const float* __restrict__ wq, const float* __restrict__ wk,
    const float* __restrict__ wv, _Float16* __restrict__ w16)
{
    int i = blockIdx.x * 256 + threadIdx.x;     // 0 .. 393215
    int p = i >> 17;                            // 131072 = 2^17 elems per W
    int j = i & 131071;
    const float* src = (p == 0) ? wq : ((p == 1) ? wk : wv);
    float f = src[j];
    if (p == 0) f *= 0.08838834764831845f;      // 1/sqrt(128) folded into Wq
    w16[i] = (_Float16)f;
}

// ---------------------------------------------------------------------------
// Kernel 2: projection GEMM, barrier-free K-loop, explicit SW pipeline.
// out[m][n] = sum_k x[m][k] * W[n][k], fp16 MFMA, fp32 accum.
// Block: 256 threads = 4 waves x 16 rows (64 rows/block). grid (256,3)
// -> 768 blocks = 3/CU = 12 waves/CU = 3 waves/SIMD (2x round-2 occupancy).
// Distance-1 register double-buffer prefetch of BOTH x (HBM) and W (L2):
// loads for step k+1 are issued before the MFMAs of step k, so ~2 steps of
// loads are in flight per wave; x3 waves/SIMD covers ~6 steps of latency.
// Named bA/bB buffers + static unroll keep everything in registers (no
// runtime-indexed arrays -> no scratch).
// p=0 -> q[s][d], p=1 -> k[s][d], p=2 -> v stored transposed vt[d][s].
// ---------------------------------------------------------------------------
__global__ __launch_bounds__(256) void proj_kernel(
    const float* __restrict__ xq, const float* __restrict__ xk,
    const float* __restrict__ xv, const _Float16* __restrict__ w16,
    _Float16* __restrict__ qws, _Float16* __restrict__ kws, _Float16* __restrict__ vtws)
{
    const int p = blockIdx.y;
    const float* __restrict__ x = (p == 0) ? xq : ((p == 1) ? xk : xv);
    const _Float16* __restrict__ w = w16 + p * 131072;

    const int mtile = blockIdx.x;               // [0,256): 64 rows each
    const int m0 = mtile << 6;
    const int t = threadIdx.x;
    const int wv_ = t >> 6;                     // 4 waves, 16 rows each
    const int lane = t & 63;
    const int l15 = lane & 15, g = lane >> 4;
    const int mw = m0 + wv_ * 16;               // this wave's 16 rows

    f32x4 acc[8];
#pragma unroll
    for (int nt = 0; nt < 8; ++nt) acc[nt] = (f32x4){0.f, 0.f, 0.f, 0.f};

    // A-frag: row = l15, k = g*8..g*8+8 within each 32-k step
    const float* x0 = x + (size_t)(mw + l15) * 1024 + g * 8;
    // B-frag: row (N) = nt*16 + l15, same k slice
    const _Float16* wb = w + (size_t)l15 * 1024 + g * 8;

    // ---- pipeline prologue: load step 0 ----
    f32x4 a0 = *(const f32x4*)(x0);
    f32x4 a1 = *(const f32x4*)(x0 + 4);
    f16x8 bA[8], bB[8];
#pragma unroll
    for (int nt = 0; nt < 8; ++nt)
        bA[nt] = *(const f16x8*)(wb + (size_t)nt * 16384);

    for (int ks = 0; ks < 32; ks += 2) {
        // even step: prefetch ks+1 -> (a2,a3,bB), then MFMAs on (a0,a1,bA)
        f32x4 a2 = *(const f32x4*)(x0 + ks * 32 + 32);
        f32x4 a3 = *(const f32x4*)(x0 + ks * 32 + 36);
#pragma unroll
        for (int nt = 0; nt < 8; ++nt)
            bB[nt] = *(const f16x8*)(wb + (size_t)nt * 16384 + ks * 32 + 32);
        f16x8 af;
#pragma unroll
        for (int j = 0; j < 4; ++j) { af[j] = (_Float16)a0[j]; af[4 + j] = (_Float16)a1[j]; }
#pragma unroll
        for (int nt = 0; nt < 8; ++nt)
            acc[nt] = __builtin_amdgcn_mfma_f32_16x16x32_f16(af, bA[nt], acc[nt], 0, 0, 0);

        // odd step: prefetch ks+2 -> (a0,a1,bA), then MFMAs on (a2,a3,bB)
        if (ks + 2 < 32) {
            a0 = *(const f32x4*)(x0 + ks * 32 + 64);
            a1 = *(const f32x4*)(x0 + ks * 32 + 68);
#pragma unroll
            for (int nt = 0; nt < 8; ++nt)
                bA[nt] = *(const f16x8*)(wb + (size_t)nt * 16384 + ks * 32 + 64);
        }
        f16x8 ag;
#pragma unroll
        for (int j = 0; j < 4; ++j) { ag[j] = (_Float16)a2[j]; ag[4 + j] = (_Float16)a3[j]; }
#pragma unroll
        for (int nt = 0; nt < 8; ++nt)
            acc[nt] = __builtin_amdgcn_mfma_f32_16x16x32_f16(ag, bB[nt], acc[nt], 0, 0, 0);
    }

    // epilogue: C frags -> LDS (transposed for p==2) -> coalesced f16x8 stores
    // p<2: [64][136] (8704); p==2: [128][72] (9216). Only barrier in kernel.
    __shared__ __align__(16) _Float16 olds[9216];
#pragma unroll
    for (int nt = 0; nt < 8; ++nt)
#pragma unroll
        for (int r = 0; r < 4; ++r) {
            int rowl = wv_ * 16 + g * 4 + r;            // C row = (lane>>4)*4 + reg
            int col = nt * 16 + l15;                    // C col = lane&15
            _Float16 v = (_Float16)acc[nt][r];
            if (p < 2) olds[rowl * 136 + col] = v;
            else       olds[col * 72 + rowl] = v;       // transpose for vt
        }
    __syncthreads();

    if (p < 2) {
#pragma unroll
        for (int i = 0; i < 4; ++i) {
            int idx = i * 256 + t;
            int row = idx >> 4, ck = idx & 15;          // 64 rows x 16 chunks
            f16x8 v = *(const f16x8*)(olds + row * 136 + ck * 8);
            _Float16* dst = ((p == 0) ? qws : kws) + (size_t)(m0 + row) * 128 + ck * 8;
            *(f16x8*)dst = v;
        }
    } else {
        const int bq = mtile >> 5, s0 = (mtile & 31) << 6;
#pragma unroll
        for (int i = 0; i < 4; ++i) {
            int idx = i * 256 + t;
            int row = idx >> 3, ck = idx & 7;           // 128 d-rows x 8 chunks
            f16x8 v = *(const f16x8*)(olds + row * 72 + ck * 8);
            _Float16* dst = vtws + ((size_t)(bq * 128 + row)) * 2048 + s0 + ck * 8;
            *(f16x8*)dst = v;
        }
    }
}

// ---------------------------------------------------------------------------
// Kernel 3: flash attention with runtime K-split (flash-decoding).
// BLOCK_M=64 (4 waves x 16 rows), BLOCK_N=64.  grid = 256 * nsplit.
// nsplit==1: write normalized out.  nsplit>1: write unnormalized O + (m,l).
// ---------------------------------------------------------------------------
__global__ __launch_bounds__(256) void flash_kernel(
    const _Float16* __restrict__ qws, const _Float16* __restrict__ kws,
    const _Float16* __restrict__ vtws, const int* __restrict__ mask,
    float* __restrict__ out, float* __restrict__ part, float* __restrict__ mlbuf,
    int ktp)                                    // K-tiles per split (32/nsplit)
{
    const int bb = blockIdx.x & 7;
    const int rest = blockIdx.x >> 3;
    const int mtile = rest & 31;
    const int jsplit = rest >> 5;
    const int sq0 = mtile << 6;
    const int t = threadIdx.x;
    const int wv_ = t >> 6;
    const int lane = t & 63;
    const int l15 = lane & 15, g = lane >> 4;

    // LDS: k[64][136] (8704) | vt[128][72] (9216) | p[4 waves][16][72] (4608)
    __shared__ __align__(16) _Float16 smem[22528];
    _Float16* klds = smem;
    _Float16* vtlds = smem + 8704;
    _Float16* plds = smem + 17920 + wv_ * 1152; // wave-private

    // Q fragments (A-layout, registers, pre-scaled by 1/sqrt(dk) via Wq)
    f16x8 qf[4];
    {
        const _Float16* qp = qws + ((size_t)(bb * 2048 + sq0 + wv_ * 16 + l15)) * 128 + g * 8;
#pragma unroll
        for (int ks = 0; ks < 4; ++ks) qf[ks] = *(const f16x8*)(qp + ks * 32);
    }

    f32x4 o[8];
#pragma unroll
    for (int nt = 0; nt < 8; ++nt) o[nt] = (f32x4){0.f, 0.f, 0.f, 0.f};
    float m_run[4], l_run[4];
#pragma unroll
    for (int r = 0; r < 4; ++r) { m_run[r] = -__builtin_inff(); l_run[r] = 0.f; }

    const int* mbase = mask + ((size_t)(bb * 2048 + sq0 + wv_ * 16 + g * 4)) * 2048 + l15;

    const int kt_begin = jsplit * ktp, kt_end = kt_begin + ktp;
    for (int kt = kt_begin; kt < kt_end; ++kt) {
        const int n0 = kt << 6;
        __syncthreads();
        // stage K tile [64][128] and Vt tile [128][64] (fp16, padded rows)
#pragma unroll
        for (int i = 0; i < 8; ++i) {
            int idx = i * 256 + t;
            if (idx < 1024) {
                int row = idx >> 4, ck = idx & 15;
                *(f16x8*)(klds + row * 136 + ck * 8) =
                    *(const f16x8*)(kws + ((size_t)(bb * 2048 + n0 + row)) * 128 + ck * 8);
            } else {
                int v = idx - 1024;
                int row = v >> 3, ck = v & 7;
                *(f16x8*)(vtlds + row * 72 + ck * 8) =
                    *(const f16x8*)(vtws + ((size_t)(bb * 128 + row)) * 2048 + n0 + ck * 8);
            }
        }
        __syncthreads();

        // mask prefetch (in flight during QK MFMAs)
        int mv[4][4];
#pragma unroll
        for (int nt = 0; nt < 4; ++nt)
#pragma unroll
            for (int r = 0; r < 4; ++r)
                mv[nt][r] = mbase[(size_t)r * 2048 + n0 + nt * 16];

        // S = Q K^T  (pre-scaled)
        f32x4 sf[4];
#pragma unroll
        for (int nt = 0; nt < 4; ++nt) sf[nt] = (f32x4){0.f, 0.f, 0.f, 0.f};
#pragma unroll
        for (int nt = 0; nt < 4; ++nt) {
            const _Float16* kp = klds + (nt * 16 + l15) * 136 + g * 8;
#pragma unroll
            for (int ks = 0; ks < 4; ++ks) {
                f16x8 bfk = *(const f16x8*)(kp + ks * 32);
                sf[nt] = __builtin_amdgcn_mfma_f32_16x16x32_f16(qf[ks], bfk, sf[nt], 0, 0, 0);
            }
        }

        // online softmax (rows: g*4+r, reduce across the 16 l15 lanes)
        float mx[4], mnew[4], alpha[4], psum[4];
#pragma unroll
        for (int r = 0; r < 4; ++r)
            mx[r] = fmaxf(fmaxf(sf[0][r], sf[1][r]), fmaxf(sf[2][r], sf[3][r]));
#pragma unroll
        for (int off = 1; off < 16; off <<= 1)
#pragma unroll
            for (int r = 0; r < 4; ++r)
                mx[r] = fmaxf(mx[r], __shfl_xor(mx[r], off, 64));
#pragma unroll
        for (int r = 0; r < 4; ++r) {
            mnew[r] = fmaxf(m_run[r], mx[r]);
            alpha[r] = exp2f((m_run[r] - mnew[r]) * L2E);
            psum[r] = 0.f;
        }
#pragma unroll
        for (int nt = 0; nt < 4; ++nt)
#pragma unroll
            for (int r = 0; r < 4; ++r) {
                float pv = exp2f((sf[nt][r] - mnew[r]) * L2E);
                pv = mv[nt][r] ? pv : 0.f;               // mask after exp: exact
                psum[r] += pv;
                plds[(g * 4 + r) * 72 + nt * 16 + l15] = (_Float16)pv;
            }
#pragma unroll
        for (int off = 1; off < 16; off <<= 1)
#pragma unroll
            for (int r = 0; r < 4; ++r)
                psum[r] += __shfl_xor(psum[r], off, 64);
#pragma unroll
        for (int r = 0; r < 4; ++r) {
            l_run[r] = l_run[r] * alpha[r] + psum[r];
            m_run[r] = mnew[r];
        }
#pragma unroll
        for (int nt = 0; nt < 8; ++nt)
#pragma unroll
            for (int r = 0; r < 4; ++r) o[nt][r] *= alpha[r];

        // P: C-layout -> A-layout via wave-private LDS
        f16x8 pa[2];
#pragma unroll
        for (int ks2 = 0; ks2 < 2; ++ks2)
            pa[ks2] = *(const f16x8*)(plds + l15 * 72 + ks2 * 32 + g * 8);

        // O += P V
#pragma unroll
        for (int nt2 = 0; nt2 < 8; ++nt2) {
            const _Float16* vp = vtlds + (nt2 * 16 + l15) * 72 + g * 8;
#pragma unroll
            for (int ks2 = 0; ks2 < 2; ++ks2) {
                f16x8 bfv = *(const f16x8*)(vp + ks2 * 32);
                o[nt2] = __builtin_amdgcn_mfma_f32_16x16x32_f16(pa[ks2], bfv, o[nt2], 0, 0, 0);
            }
        }
    }

    if (part == nullptr) {
        // single-split: normalize + store fp32
        float inv[4];
#pragma unroll
        for (int r = 0; r < 4; ++r) inv[r] = 1.0f / l_run[r];
#pragma unroll
        for (int nt2 = 0; nt2 < 8; ++nt2)
#pragma unroll
            for (int r = 0; r < 4; ++r)
                out[((size_t)(bb * 2048 + sq0 + wv_ * 16 + g * 4 + r)) * 128 + nt2 * 16 + l15] =
                    o[nt2][r] * inv[r];
    } else {
        // write unnormalized partial O + per-row (m, l)
#pragma unroll
        for (int nt2 = 0; nt2 < 8; ++nt2)
#pragma unroll
            for (int r = 0; r < 4; ++r) {
                size_t rowg = (size_t)(bb * 2048 + sq0 + wv_ * 16 + g * 4 + r);
                part[((size_t)jsplit * 16384 + rowg) * 128 + nt2 * 16 + l15] = o[nt2][r];
            }
        if (l15 == 0) {
#pragma unroll
            for (int r = 0; r < 4; ++r) {
                size_t rowg = (size_t)(bb * 2048 + sq0 + wv_ * 16 + g * 4 + r);
                mlbuf[((size_t)jsplit * 16384 + rowg) * 2]     = m_run[r];
                mlbuf[((size_t)jsplit * 16384 + rowg) * 2 + 1] = l_run[r];
            }
        }
    }
}

// ---------------------------------------------------------------------------
// Kernel 4: merge K-split partials.  out = (sum_j e^{m_j-m} O_j) / sum_j e^{m_j-m} l_j
// Block 256 = 8 rows x 32 lanes x f32x4.  grid 2048.
// ---------------------------------------------------------------------------
__global__ __launch_bounds__(256) void merge_kernel(
    const float* __restrict__ part, const float* __restrict__ mlbuf,
    float* __restrict__ out, int J)
{
    int t = threadIdx.x;
    size_t row = (size_t)blockIdx.x * 8 + (t >> 5);
    int c = (t & 31) * 4;
    float mj[4];
    float m = -__builtin_inff();
    for (int j = 0; j < J; ++j) {
        mj[j] = mlbuf[((size_t)j * 16384 + row) * 2];
        m = fmaxf(m, mj[j]);
    }
    float l = 0.f;
    f32x4 acc = (f32x4){0.f, 0.f, 0.f, 0.f};
    for (int j = 0; j < J; ++j) {
        float w = exp2f((mj[j] - m) * L2E);
        l += w * mlbuf[((size_t)j * 16384 + row) * 2 + 1];
        f32x4 v = *(const f32x4*)(part + ((size_t)j * 16384 + row) * 128 + c);
#pragma unroll
        for (int e = 0; e < 4; ++e) acc[e] += w * v[e];
    }
    float inv = 1.0f / l;
#pragma unroll
    for (int e = 0; e < 4; ++e) acc[e] *= inv;
    *(f32x4*)(out + row * 128 + c) = acc;
}

// ---------------------------------------------------------------------------
extern "C" void kernel_launch(void* const* d_in, const int* in_sizes, int n_in,
                              void* d_out, int out_size, void* d_ws, size_t ws_size,
                              hipStream_t stream)
{
    const float* query = (const float*)d_in[0];
    const float* key   = (const float*)d_in[1];
    const float* value = (const float*)d_in[2];
    const int*   mask  = (const int*)d_in[3];
    const float* Wq    = (const float*)d_in[4];
    const float* Wk    = (const float*)d_in[5];
    const float* Wv    = (const float*)d_in[6];
    float* out = (float*)d_out;

    _Float16* w16 = (_Float16*)d_ws;
    _Float16* qws = w16 + WS_Q;
    _Float16* kws = w16 + WS_K;
    _Float16* vtws = w16 + WS_VT;

    // choose K-split from workspace budget: per split 16384*128*4 + 16384*8 B
    const size_t per_split = 16384ull * 128 * 4 + 16384ull * 8;  // 8519680
    int J = 1;
    if (ws_size >= WS_F16_BYTES + 4 * per_split)      J = 4;
    else if (ws_size >= WS_F16_BYTES + 2 * per_split) J = 2;
    float* part = (J > 1) ? (float*)((char*)d_ws + WS_F16_BYTES) : nullptr;
    float* mlbuf = (J > 1) ? (part + (size_t)J * 16384 * 128) : nullptr;

    wconv_kernel<<<1536, 256, 0, stream>>>(Wq, Wk, Wv, w16);
    proj_kernel<<<dim3(256, 3), 256, 0, stream>>>(query, key, value, w16, qws, kws, vtws);
    flash_kernel<<<256 * J, 256, 0, stream>>>(qws, kws, vtws, mask, out, part, mlbuf, 32 / J);
    if (J > 1) merge_kernel<<<2048, 256, 0, stream>>>(part, mlbuf, out, J);
}

// Round 5
// 381.648 us; speedup vs baseline: 1.1781x; 1.1781x over previous
//
#include <hip/hip_runtime.h>
#include <hip/hip_fp16.h>

// B=8, S=2048, DMODEL=1024, DK=128
#define SEQ 2048
#define DMODEL 1024
#define DK 128

typedef _Float16 f16x8 __attribute__((ext_vector_type(8)));
typedef float    f32x4 __attribute__((ext_vector_type(4)));

#define L2E 1.44269504088896340736f

// ---------------- workspace element offsets (fp16 elements) ----------------
// w16: [3][128][1024]           at 0        (393216)
// q:   [16384][128]             at 393216
// k:   [16384][128]             at 2490368
// vt:  [8][128][2048]           at 4587520  (end 6684672 f16 = 13369344 B)
// then fp32 partials: Opart[J][16384][128], ml[J][16384][2]
#define WS_Q  393216
#define WS_K  2490368
#define WS_VT 4587520
#define WS_F16_BYTES 13369344ull

// ---------------------------------------------------------------------------
// Kernel 1: convert Wq/Wk/Wv fp32 -> fp16.  Scale 1/sqrt(dk) folded into Wq.
// ---------------------------------------------------------------------------
__global__ __launch_bounds__(256) void wconv_kernel(
    const float* __restrict__ wq, const float* __restrict__ wk,
    const float* __restrict__ wv, _Float16* __restrict__ w16)
{
    int i = blockIdx.x * 256 + threadIdx.x;     // 0 .. 393215
    int p = i >> 17;                            // 131072 = 2^17 elems per W
    int j = i & 131071;
    const float* src = (p == 0) ? wq : ((p == 1) ? wk : wv);
    float f = src[j];
    if (p == 0) f *= 0.08838834764831845f;      // 1/sqrt(128) folded into Wq
    w16[i] = (_Float16)f;
}

// ---------------------------------------------------------------------------
// Kernel 2: projection GEMM, LDS-shared W, T14 async-stage, 1 barrier/tile.
// out[m][n] = sum_k x[m][k] * W[n][k], fp16 MFMA, fp32 accum.
// Block: 256 threads = 4 waves x 16 rows (64 rows/block). grid (256,3)
// -> 768 blocks = 3/CU = 12 waves/CU.
// W shared via LDS (kills the per-wave 256KB W redundancy of r2/r3).
// BK=64 double-buffer, 16 k-tiles (16*64 = 1024 = DMODEL; r4 bug was 8).
// Issue-early/write-late: global loads for tile t+1 issue right after the
// barrier of tile t, ds_write at the start of tile t+1 -> each load gets a
// full compute phase (~16 MFMA + 16 ds_read) to land.  One barrier/tile.
// LDS rows padded to 72 f16 (144B) -> conflict-free diagonal bank pattern.
// Fully unrolled -> all staging regs statically indexed (no scratch).
// p=0 -> q[s][d], p=1 -> k[s][d], p=2 -> v stored transposed vt[d][s].
// ---------------------------------------------------------------------------
__global__ __launch_bounds__(256, 3) void proj_kernel(
    const float* __restrict__ xq, const float* __restrict__ xk,
    const float* __restrict__ xv, const _Float16* __restrict__ w16,
    _Float16* __restrict__ qws, _Float16* __restrict__ kws, _Float16* __restrict__ vtws)
{
    const int p = blockIdx.y;
    const float* __restrict__ x = (p == 0) ? xq : ((p == 1) ? xk : xv);
    const _Float16* __restrict__ w = w16 + p * 131072;

    const int mtile = blockIdx.x;               // [0,256): 64 rows each
    const int m0 = mtile << 6;
    const int t = threadIdx.x;
    const int wv_ = t >> 6;                     // 4 waves, 16 rows each
    const int lane = t & 63;
    const int l15 = lane & 15, g = lane >> 4;
    const int mw = m0 + wv_ * 16;               // this wave's 16 rows

    // LDS: two W buffers [128 n][72 f16] (pad 64->72 = 144B rows).
    // 18432 f16 = 36 KB; epilogue olds aliases the same array.
    __shared__ __align__(16) _Float16 smem[18432];

    f32x4 acc[8];
#pragma unroll
    for (int nt = 0; nt < 8; ++nt) acc[nt] = (f32x4){0.f, 0.f, 0.f, 0.f};

    // A: row = l15 (per wave), k-slice g*8 within each 32-k step
    const float* x0 = x + (size_t)(mw + l15) * 1024 + g * 8;
    // W staging: thread handles chunks i = j*256+t (j=0..3); row=i>>3, kc=i&7
    const int srow = t >> 3, skc = t & 7;       // chunk j adds 32 rows
    const _Float16* wsrc = w + (size_t)srow * 1024 + skc * 8;
    const int sdst = srow * 72 + skc * 8;

    // staging registers (statically indexed via full unroll)
    f16x8 wreg[2][4];
    f32x4 areg[2][4];

    // ---- prologue: issue tile-0 loads ----
#pragma unroll
    for (int j = 0; j < 4; ++j)
        wreg[0][j] = *(const f16x8*)(wsrc + (size_t)j * 32 * 1024);
#pragma unroll
    for (int s = 0; s < 2; ++s) {
        areg[0][s * 2]     = *(const f32x4*)(x0 + s * 32);
        areg[0][s * 2 + 1] = *(const f32x4*)(x0 + s * 32 + 4);
    }

#pragma unroll
    for (int kt = 0; kt < 16; ++kt) {           // 16 k-tiles of 64 = DMODEL
        const int c = kt & 1;
        _Float16* buf = smem + c * 9216;

        // write phase: stage tile kt's W regs into LDS (auto vmcnt wait)
#pragma unroll
        for (int j = 0; j < 4; ++j)
            *(f16x8*)(buf + j * 32 * 72 + sdst) = wreg[c][j];
        __syncthreads();

        // issue-early: global loads for tile kt+1 (land during compute)
        if (kt < 15) {
#pragma unroll
            for (int j = 0; j < 4; ++j)
                wreg[c ^ 1][j] = *(const f16x8*)(wsrc + (size_t)j * 32 * 1024
                                                 + (kt + 1) * 64);
#pragma unroll
            for (int s = 0; s < 2; ++s) {
                areg[c ^ 1][s * 2]     = *(const f32x4*)(x0 + (kt + 1) * 64 + s * 32);
                areg[c ^ 1][s * 2 + 1] = *(const f32x4*)(x0 + (kt + 1) * 64 + s * 32 + 4);
            }
        }

        // compute phase: 2 k-steps of 32, 8 n-tiles each
#pragma unroll
        for (int s = 0; s < 2; ++s) {
            f16x8 af;
#pragma unroll
            for (int j = 0; j < 4; ++j) {
                af[j]     = (_Float16)areg[c][s * 2][j];
                af[4 + j] = (_Float16)areg[c][s * 2 + 1][j];
            }
#pragma unroll
            for (int nt = 0; nt < 8; ++nt) {
                f16x8 bf = *(const f16x8*)(buf + (nt * 16 + l15) * 72 + s * 32 + g * 8);
                acc[nt] = __builtin_amdgcn_mfma_f32_16x16x32_f16(af, bf, acc[nt], 0, 0, 0);
            }
        }
    }

    // epilogue: C frags -> LDS (transposed for p==2) -> coalesced f16x8 stores
    // olds aliases smem: p<2 [64][136] (8695 max); p==2 [128][72] (9207 max).
    __syncthreads();                            // all ds_reads consumed
    _Float16* olds = smem;
#pragma unroll
    for (int nt = 0; nt < 8; ++nt)
#pragma unroll
        for (int r = 0; r < 4; ++r) {
            int rowl = wv_ * 16 + g * 4 + r;            // C row = (lane>>4)*4 + reg
            int col = nt * 16 + l15;                    // C col = lane&15
            _Float16 v = (_Float16)acc[nt][r];
            if (p < 2) olds[rowl * 136 + col] = v;
            else       olds[col * 72 + rowl] = v;       // transpose for vt
        }
    __syncthreads();

    if (p < 2) {
#pragma unroll
        for (int i = 0; i < 4; ++i) {
            int idx = i * 256 + t;
            int row = idx >> 4, ck = idx & 15;          // 64 rows x 16 chunks
            f16x8 v = *(const f16x8*)(olds + row * 136 + ck * 8);
            _Float16* dst = ((p == 0) ? qws : kws) + (size_t)(m0 + row) * 128 + ck * 8;
            *(f16x8*)dst = v;
        }
    } else {
        const int bq = mtile >> 5, s0 = (mtile & 31) << 6;
#pragma unroll
        for (int i = 0; i < 4; ++i) {
            int idx = i * 256 + t;
            int row = idx >> 3, ck = idx & 7;           // 128 d-rows x 8 chunks
            f16x8 v = *(const f16x8*)(olds + row * 72 + ck * 8);
            _Float16* dst = vtws + ((size_t)(bq * 128 + row)) * 2048 + s0 + ck * 8;
            *(f16x8*)dst = v;
        }
    }
}

// ---------------------------------------------------------------------------
// Kernel 3: flash attention with runtime K-split (flash-decoding).
// BLOCK_M=64 (4 waves x 16 rows), BLOCK_N=64.  grid = 256 * nsplit.
// nsplit==1: write normalized out.  nsplit>1: write unnormalized O + (m,l).
// ---------------------------------------------------------------------------
__global__ __launch_bounds__(256) void flash_kernel(
    const _Float16* __restrict__ qws, const _Float16* __restrict__ kws,
    const _Float16* __restrict__ vtws, const int* __restrict__ mask,
    float* __restrict__ out, float* __restrict__ part, float* __restrict__ mlbuf,
    int ktp)                                    // K-tiles per split (32/nsplit)
{
    const int bb = blockIdx.x & 7;
    const int rest = blockIdx.x >> 3;
    const int mtile = rest & 31;
    const int jsplit = rest >> 5;
    const int sq0 = mtile << 6;
    const int t = threadIdx.x;
    const int wv_ = t >> 6;
    const int lane = t & 63;
    const int l15 = lane & 15, g = lane >> 4;

    // LDS: k[64][136] (8704) | vt[128][72] (9216) | p[4 waves][16][72] (4608)
    __shared__ __align__(16) _Float16 smem[22528];
    _Float16* klds = smem;
    _Float16* vtlds = smem + 8704;
    _Float16* plds = smem + 17920 + wv_ * 1152; // wave-private

    // Q fragments (A-layout, registers, pre-scaled by 1/sqrt(dk) via Wq)
    f16x8 qf[4];
    {
        const _Float16* qp = qws + ((size_t)(bb * 2048 + sq0 + wv_ * 16 + l15)) * 128 + g * 8;
#pragma unroll
        for (int ks = 0; ks < 4; ++ks) qf[ks] = *(const f16x8*)(qp + ks * 32);
    }

    f32x4 o[8];
#pragma unroll
    for (int nt = 0; nt < 8; ++nt) o[nt] = (f32x4){0.f, 0.f, 0.f, 0.f};
    float m_run[4], l_run[4];
#pragma unroll
    for (int r = 0; r < 4; ++r) { m_run[r] = -__builtin_inff(); l_run[r] = 0.f; }

    const int* mbase = mask + ((size_t)(bb * 2048 + sq0 + wv_ * 16 + g * 4)) * 2048 + l15;

    const int kt_begin = jsplit * ktp, kt_end = kt_begin + ktp;
    for (int kt = kt_begin; kt < kt_end; ++kt) {
        const int n0 = kt << 6;
        __syncthreads();
        // stage K tile [64][128] and Vt tile [128][64] (fp16, padded rows)
#pragma unroll
        for (int i = 0; i < 8; ++i) {
            int idx = i * 256 + t;
            if (idx < 1024) {
                int row = idx >> 4, ck = idx & 15;
                *(f16x8*)(klds + row * 136 + ck * 8) =
                    *(const f16x8*)(kws + ((size_t)(bb * 2048 + n0 + row)) * 128 + ck * 8);
            } else {
                int v = idx - 1024;
                int row = v >> 3, ck = v & 7;
                *(f16x8*)(vtlds + row * 72 + ck * 8) =
                    *(const f16x8*)(vtws + ((size_t)(bb * 128 + row)) * 2048 + n0 + ck * 8);
            }
        }
        __syncthreads();

        // mask prefetch (in flight during QK MFMAs)
        int mv[4][4];
#pragma unroll
        for (int nt = 0; nt < 4; ++nt)
#pragma unroll
            for (int r = 0; r < 4; ++r)
                mv[nt][r] = mbase[(size_t)r * 2048 + n0 + nt * 16];

        // S = Q K^T  (pre-scaled)
        f32x4 sf[4];
#pragma unroll
        for (int nt = 0; nt < 4; ++nt) sf[nt] = (f32x4){0.f, 0.f, 0.f, 0.f};
#pragma unroll
        for (int nt = 0; nt < 4; ++nt) {
            const _Float16* kp = klds + (nt * 16 + l15) * 136 + g * 8;
#pragma unroll
            for (int ks = 0; ks < 4; ++ks) {
                f16x8 bfk = *(const f16x8*)(kp + ks * 32);
                sf[nt] = __builtin_amdgcn_mfma_f32_16x16x32_f16(qf[ks], bfk, sf[nt], 0, 0, 0);
            }
        }

        // online softmax (rows: g*4+r, reduce across the 16 l15 lanes)
        float mx[4], mnew[4], alpha[4], psum[4];
#pragma unroll
        for (int r = 0; r < 4; ++r)
            mx[r] = fmaxf(fmaxf(sf[0][r], sf[1][r]), fmaxf(sf[2][r], sf[3][r]));
#pragma unroll
        for (int off = 1; off < 16; off <<= 1)
#pragma unroll
            for (int r = 0; r < 4; ++r)
                mx[r] = fmaxf(mx[r], __shfl_xor(mx[r], off, 64));
#pragma unroll
        for (int r = 0; r < 4; ++r) {
            mnew[r] = fmaxf(m_run[r], mx[r]);
            alpha[r] = exp2f((m_run[r] - mnew[r]) * L2E);
            psum[r] = 0.f;
        }
#pragma unroll
        for (int nt = 0; nt < 4; ++nt)
#pragma unroll
            for (int r = 0; r < 4; ++r) {
                float pv = exp2f((sf[nt][r] - mnew[r]) * L2E);
                pv = mv[nt][r] ? pv : 0.f;               // mask after exp: exact
                psum[r] += pv;
                plds[(g * 4 + r) * 72 + nt * 16 + l15] = (_Float16)pv;
            }
#pragma unroll
        for (int off = 1; off < 16; off <<= 1)
#pragma unroll
            for (int r = 0; r < 4; ++r)
                psum[r] += __shfl_xor(psum[r], off, 64);
#pragma unroll
        for (int r = 0; r < 4; ++r) {
            l_run[r] = l_run[r] * alpha[r] + psum[r];
            m_run[r] = mnew[r];
        }
#pragma unroll
        for (int nt = 0; nt < 8; ++nt)
#pragma unroll
            for (int r = 0; r < 4; ++r) o[nt][r] *= alpha[r];

        // P: C-layout -> A-layout via wave-private LDS
        f16x8 pa[2];
#pragma unroll
        for (int ks2 = 0; ks2 < 2; ++ks2)
            pa[ks2] = *(const f16x8*)(plds + l15 * 72 + ks2 * 32 + g * 8);

        // O += P V
#pragma unroll
        for (int nt2 = 0; nt2 < 8; ++nt2) {
            const _Float16* vp = vtlds + (nt2 * 16 + l15) * 72 + g * 8;
#pragma unroll
            for (int ks2 = 0; ks2 < 2; ++ks2) {
                f16x8 bfv = *(const f16x8*)(vp + ks2 * 32);
                o[nt2] = __builtin_amdgcn_mfma_f32_16x16x32_f16(pa[ks2], bfv, o[nt2], 0, 0, 0);
            }
        }
    }

    if (part == nullptr) {
        // single-split: normalize + store fp32
        float inv[4];
#pragma unroll
        for (int r = 0; r < 4; ++r) inv[r] = 1.0f / l_run[r];
#pragma unroll
        for (int nt2 = 0; nt2 < 8; ++nt2)
#pragma unroll
            for (int r = 0; r < 4; ++r)
                out[((size_t)(bb * 2048 + sq0 + wv_ * 16 + g * 4 + r)) * 128 + nt2 * 16 + l15] =
                    o[nt2][r] * inv[r];
    } else {
        // write unnormalized partial O + per-row (m, l)
#pragma unroll
        for (int nt2 = 0; nt2 < 8; ++nt2)
#pragma unroll
            for (int r = 0; r < 4; ++r) {
                size_t rowg = (size_t)(bb * 2048 + sq0 + wv_ * 16 + g * 4 + r);
                part[((size_t)jsplit * 16384 + rowg) * 128 + nt2 * 16 + l15] = o[nt2][r];
            }
        if (l15 == 0) {
#pragma unroll
            for (int r = 0; r < 4; ++r) {
                size_t rowg = (size_t)(bb * 2048 + sq0 + wv_ * 16 + g * 4 + r);
                mlbuf[((size_t)jsplit * 16384 + rowg) * 2]     = m_run[r];
                mlbuf[((size_t)jsplit * 16384 + rowg) * 2 + 1] = l_run[r];
            }
        }
    }
}

// ---------------------------------------------------------------------------
// Kernel 4: merge K-split partials.  out = (sum_j e^{m_j-m} O_j) / sum_j e^{m_j-m} l_j
// Block 256 = 8 rows x 32 lanes x f32x4.  grid 2048.
// ---------------------------------------------------------------------------
__global__ __launch_bounds__(256) void merge_kernel(
    const float* __restrict__ part, const float* __restrict__ mlbuf,
    float* __restrict__ out, int J)
{
    int t = threadIdx.x;
    size_t row = (size_t)blockIdx.x * 8 + (t >> 5);
    int c = (t & 31) * 4;
    float mj[4];
    float m = -__builtin_inff();
    for (int j = 0; j < J; ++j) {
        mj[j] = mlbuf[((size_t)j * 16384 + row) * 2];
        m = fmaxf(m, mj[j]);
    }
    float l = 0.f;
    f32x4 acc = (f32x4){0.f, 0.f, 0.f, 0.f};
    for (int j = 0; j < J; ++j) {
        float w = exp2f((mj[j] - m) * L2E);
        l += w * mlbuf[((size_t)j * 16384 + row) * 2 + 1];
        f32x4 v = *(const f32x4*)(part + ((size_t)j * 16384 + row) * 128 + c);
#pragma unroll
        for (int e = 0; e < 4; ++e) acc[e] += w * v[e];
    }
    float inv = 1.0f / l;
#pragma unroll
    for (int e = 0; e < 4; ++e) acc[e] *= inv;
    *(f32x4*)(out + row * 128 + c) = acc;
}

// ---------------------------------------------------------------------------
extern "C" void kernel_launch(void* const* d_in, const int* in_sizes, int n_in,
                              void* d_out, int out_size, void* d_ws, size_t ws_size,
                              hipStream_t stream)
{
    const float* query = (const float*)d_in[0];
    const float* key   = (const float*)d_in[1];
    const float* value = (const float*)d_in[2];
    const int*   mask  = (const int*)d_in[3];
    const float* Wq    = (const float*)d_in[4];
    const float* Wk    = (const float*)d_in[5];
    const float* Wv    = (const float*)d_in[6];
    float* out = (float*)d_out;

    _Float16* w16 = (_Float16*)d_ws;
    _Float16* qws = w16 + WS_Q;
    _Float16* kws = w16 + WS_K;
    _Float16* vtws = w16 + WS_VT;

    // choose K-split from workspace budget: per split 16384*128*4 + 16384*8 B
    const size_t per_split = 16384ull * 128 * 4 + 16384ull * 8;  // 8519680
    int J = 1;
    if (ws_size >= WS_F16_BYTES + 4 * per_split)      J = 4;
    else if (ws_size >= WS_F16_BYTES + 2 * per_split) J = 2;
    float* part = (J > 1) ? (float*)((char*)d_ws + WS_F16_BYTES) : nullptr;
    float* mlbuf = (J > 1) ? (part + (size_t)J * 16384 * 128) : nullptr;

    wconv_kernel<<<1536, 256, 0, stream>>>(Wq, Wk, Wv, w16);
    proj_kernel<<<dim3(256, 3), 256, 0, stream>>>(query, key, value, w16, qws, kws, vtws);
    flash_kernel<<<256 * J, 256, 0, stream>>>(qws, kws, vtws, mask, out, part, mlbuf, 32 / J);
    if (J > 1) merge_kernel<<<2048, 256, 0, stream>>>(part, mlbuf, out, J);
}